// Round 5
// baseline (177.146 us; speedup 1.0000x reference)
//
#include <hip/hip_runtime.h>
#include <math.h>

// B=4, T=2048, N_EMBD=1024, HEAD=64.
// Reference multiplies scores by sqrt(64)=8; we fold 8*log2(e) into q and use exp2.
#define NE 1024
#define HS 64
#define TT 2048
#define QSC 11.541560327111707f   // 8 * log2(e)

typedef __bf16    v8bf __attribute__((ext_vector_type(8)));
typedef _Float16  v8h  __attribute__((ext_vector_type(8)));
typedef float     v4f  __attribute__((ext_vector_type(4)));

#define MFMA_BF(a, b, c)  __builtin_amdgcn_mfma_f32_16x16x32_bf16((a), (b), (c), 0, 0, 0)
#define MFMA_F16(a, b, c) __builtin_amdgcn_mfma_f32_16x16x32_f16((a), (b), (c), 0, 0, 0)

// ---------------------------------------------------------------------------
// Prep: split Wq|Wk|Wv into transposed hi/lo bf16 wt[n][k] (n=0..191) via LDS
// transpose so both the W read and the wt writes are fully coalesced.
// ---------------------------------------------------------------------------
__global__ __launch_bounds__(256) void prep_w(
    const float* __restrict__ Wq, const float* __restrict__ Wk,
    const float* __restrict__ Wv, __bf16* __restrict__ wth, __bf16* __restrict__ wtl)
{
    __shared__ float t[64][65];
    const int k0 = blockIdx.x * 64, n0 = blockIdx.y * 64;
    const float* W = (n0 == 0) ? Wq : ((n0 == 64) ? Wk : Wv);
    const int tid = threadIdx.x;
    const int c = tid & 63, r4 = tid >> 6;
    #pragma unroll
    for (int p = 0; p < 16; ++p) {
        const int k = p * 4 + r4;
        t[k][c] = W[(size_t)(k0 + k) * HS + c];
    }
    __syncthreads();
    #pragma unroll
    for (int p = 0; p < 16; ++p) {
        const int n = p * 4 + r4;
        const float w = t[c][n];
        const __bf16 h = (__bf16)w;
        const size_t o = (size_t)(n0 + n) * NE + k0 + c;
        wth[o] = h;
        wtl[o] = (__bf16)(w - (float)h);
    }
}

// ---------------------------------------------------------------------------
// Projection GEMM, split-precision bf16 MFMA, intra-block split-K.
// Grid (128 m-blocks, 4 n-blocks), 512 threads = 8 waves.
// Wave (r, h): rows m0+16r..+15, k-half h (512 k each, 16 steps of 32).
// A fragments direct from global, prefetch depth 3; W hi/lo prefetch depth 2
// (L2-hot: same 192 KB slice for all m-blocks). NO barriers in the K-loop.
// K-halves merged via LDS once; epilogue by the h=0 waves.
// ---------------------------------------------------------------------------
__global__ __launch_bounds__(512, 4) void proj(
    const float* __restrict__ x, const __bf16* __restrict__ wth,
    const __bf16* __restrict__ wtl,
    const float* __restrict__ bq, const float* __restrict__ bk,
    const float* __restrict__ bv,
    __bf16* __restrict__ qh, __bf16* __restrict__ ql,
    __bf16* __restrict__ kh, __bf16* __restrict__ kl,
    _Float16* __restrict__ vt)
{
    __shared__ float part[64 * 52];                  // 13.3 KB merge buffer

    const int tid = threadIdx.x, lane = tid & 63, w = tid >> 6;
    const int r = w & 3, h = w >> 2;
    const int quad = lane >> 4, l16 = lane & 15;
    const int m0 = blockIdx.x * 64, n0 = blockIdx.y * 48;

    const float*  xp  = x   + (size_t)(m0 + r * 16 + l16) * NE + h * 512 + quad * 8;
    const __bf16* bhp = wth + (size_t)(n0 + l16) * NE + h * 512 + quad * 8;
    const __bf16* blp = wtl + (size_t)(n0 + l16) * NE + h * 512 + quad * 8;

    v4f acc[3];
    #pragma unroll
    for (int i = 0; i < 3; ++i) acc[i] = (v4f){0.f, 0.f, 0.f, 0.f};

    // prefetch pipeline: x depth 3, W depth 2
    float4 xa[3][2];
    v8bf pbh[2][3], pbl[2][3];
    #pragma unroll
    for (int d = 0; d < 3; ++d) {
        xa[d][0] = *(const float4*)(xp + d * 32);
        xa[d][1] = *(const float4*)(xp + d * 32 + 4);
    }
    #pragma unroll
    for (int d = 0; d < 2; ++d)
        #pragma unroll
        for (int j = 0; j < 3; ++j) {
            pbh[d][j] = *(const v8bf*)(bhp + (size_t)j * 16 * NE + d * 32);
            pbl[d][j] = *(const v8bf*)(blp + (size_t)j * 16 * NE + d * 32);
        }

    for (int ks = 0; ks < 16; ++ks) {
        const int cx = ks % 3, cw = ks & 1;
        // grab current values
        const float4 c0 = xa[cx][0], c1 = xa[cx][1];
        v8bf cbh[3], cbl[3];
        #pragma unroll
        for (int j = 0; j < 3; ++j) { cbh[j] = pbh[cw][j]; cbl[j] = pbl[cw][j]; }
        // issue next prefetches into freed slots
        if (ks + 3 < 16) {
            xa[cx][0] = *(const float4*)(xp + (ks + 3) * 32);
            xa[cx][1] = *(const float4*)(xp + (ks + 3) * 32 + 4);
        }
        if (ks + 2 < 16) {
            #pragma unroll
            for (int j = 0; j < 3; ++j) {
                pbh[cw][j] = *(const v8bf*)(bhp + (size_t)j * 16 * NE + (ks + 2) * 32);
                pbl[cw][j] = *(const v8bf*)(blp + (size_t)j * 16 * NE + (ks + 2) * 32);
            }
        }
        // convert A to hi/lo bf16
        const float av[8] = {c0.x, c0.y, c0.z, c0.w, c1.x, c1.y, c1.z, c1.w};
        v8bf ah, al;
        #pragma unroll
        for (int i = 0; i < 8; ++i) {
            const __bf16 hh = (__bf16)av[i];
            ah[i] = hh;
            al[i] = (__bf16)(av[i] - (float)hh);
        }
        acc[0] = MFMA_BF(ah, cbh[0], acc[0]);
        acc[1] = MFMA_BF(ah, cbh[1], acc[1]);
        acc[2] = MFMA_BF(ah, cbh[2], acc[2]);
        acc[0] = MFMA_BF(ah, cbl[0], acc[0]);
        acc[1] = MFMA_BF(ah, cbl[1], acc[1]);
        acc[2] = MFMA_BF(ah, cbl[2], acc[2]);
        acc[0] = MFMA_BF(al, cbh[0], acc[0]);
        acc[1] = MFMA_BF(al, cbh[1], acc[1]);
        acc[2] = MFMA_BF(al, cbh[2], acc[2]);
    }

    // merge k-halves: h=1 writes partials, h=0 adds
    if (h == 1) {
        #pragma unroll
        for (int j = 0; j < 3; ++j)
            #pragma unroll
            for (int reg = 0; reg < 4; ++reg)
                part[(r * 16 + quad * 4 + reg) * 52 + j * 16 + l16] = acc[j][reg];
    }
    __syncthreads();
    if (h == 1) return;

    #pragma unroll
    for (int j = 0; j < 3; ++j)
        #pragma unroll
        for (int reg = 0; reg < 4; ++reg)
            acc[j][reg] += part[(r * 16 + quad * 4 + reg) * 52 + j * 16 + l16];

    // epilogue: C layout col=l16 (within n-tile), row=quad*4+reg
    #pragma unroll
    for (int j = 0; j < 3; ++j) {
        const int n = n0 + j * 16 + l16;
        const float bias = (n < 64) ? bq[n] : ((n < 128) ? bk[n - 64] : bv[n - 128]);
        #pragma unroll
        for (int reg = 0; reg < 4; ++reg) {
            const int row = m0 + r * 16 + quad * 4 + reg;
            const float v = acc[j][reg] + bias;
            if (n < 64) {
                const float s = v * QSC;             // fold 8*log2e into q
                const __bf16 hh = (__bf16)s;
                qh[(size_t)row * HS + n] = hh;
                ql[(size_t)row * HS + n] = (__bf16)(s - (float)hh);
            } else if (n < 128) {
                const __bf16 hh = (__bf16)v;
                kh[(size_t)row * HS + n - 64] = hh;
                kl[(size_t)row * HS + n - 64] = (__bf16)(v - (float)hh);
            } else {
                const int b = row >> 11, tt = row & 2047, hc = n - 128;
                vt[((size_t)(b * HS + hc)) * TT + tt] = (_Float16)v;
            }
        }
    }
}

// ---------------------------------------------------------------------------
// Flash attention, MFMA. Block = 16 q-rows, 4 waves split the key range
// (round-robin 64-key tiles), independent online softmax, merged at the end.
// Scores arrive in log2 units (q pre-scaled) -> native exp2. Row-sums of P
// computed by 2 extra MFMAs vs an all-ones B ("ones column"), rescaled like O.
// ---------------------------------------------------------------------------
__global__ __launch_bounds__(256) void attn(
    const __bf16* __restrict__ qh, const __bf16* __restrict__ ql,
    const __bf16* __restrict__ kh, const __bf16* __restrict__ kl,
    const _Float16* __restrict__ vt, float* __restrict__ out)
{
    __shared__ __align__(16) char smem_raw[4 * 16 * 68 * 4];  // 17408 B
    _Float16* ps = (_Float16*)smem_raw;   // [w][16*72] fp16 (k-loop only)
    float*    os = (float*)smem_raw;      // [w][16*68] fp32 (merge only)
    __shared__ float sm[4][16], sl[4][16];

    const int tid = threadIdx.x, lane = tid & 63, w = tid >> 6;
    const int quad = lane >> 4, l16 = lane & 15;
    const int b = blockIdx.x & 3, qi = blockIdx.x >> 2;
    const int q0 = (127 - qi) * 16;                 // heavy tiles first

    const size_t qrow = ((size_t)b * TT + q0 + l16) * HS;
    const v8bf Qh0 = *(const v8bf*)(qh + qrow + quad * 8);
    const v8bf Qh1 = *(const v8bf*)(qh + qrow + 32 + quad * 8);
    const v8bf Ql0 = *(const v8bf*)(ql + qrow + quad * 8);
    const v8bf Ql1 = *(const v8bf*)(ql + qrow + 32 + quad * 8);

    const v8h vones = {(_Float16)1.f, (_Float16)1.f, (_Float16)1.f, (_Float16)1.f,
                       (_Float16)1.f, (_Float16)1.f, (_Float16)1.f, (_Float16)1.f};

    float mrow[4] = {-3e38f, -3e38f, -3e38f, -3e38f};
    v4f o[4], o4;
    #pragma unroll
    for (int i = 0; i < 4; ++i) o[i] = (v4f){0.f, 0.f, 0.f, 0.f};
    o4 = (v4f){0.f, 0.f, 0.f, 0.f};

    const int irow = q0 + quad * 4;                 // + reg
    const int ntk = (q0 + 16 + 63) >> 6;
    _Float16* pw = ps + w * (16 * 72);

    for (int t = w; t < ntk; t += 4) {
        const int j0 = t * 64;

        // ---- batched fragment loads: 16 K + 8 V, one vmcnt wall ----
        v8bf Kh[8], Kl[8];
        v8h  Vf[8];
        #pragma unroll
        for (int nt = 0; nt < 4; ++nt) {
            const size_t krow = ((size_t)b * TT + j0 + nt * 16 + l16) * HS;
            Kh[nt * 2]     = *(const v8bf*)(kh + krow + quad * 8);
            Kh[nt * 2 + 1] = *(const v8bf*)(kh + krow + 32 + quad * 8);
            Kl[nt * 2]     = *(const v8bf*)(kl + krow + quad * 8);
            Kl[nt * 2 + 1] = *(const v8bf*)(kl + krow + 32 + quad * 8);
        }
        #pragma unroll
        for (int nt = 0; nt < 4; ++nt) {
            const size_t vrow = ((size_t)(b * HS + nt * 16 + l16)) * TT + j0;
            Vf[nt * 2]     = *(const v8h*)(vt + vrow + quad * 8);
            Vf[nt * 2 + 1] = *(const v8h*)(vt + vrow + 32 + quad * 8);
        }

        v4f s[4];
        #pragma unroll
        for (int i = 0; i < 4; ++i) s[i] = (v4f){0.f, 0.f, 0.f, 0.f};
        #pragma unroll
        for (int nt = 0; nt < 4; ++nt) {
            s[nt] = MFMA_BF(Qh0, Kh[nt * 2],     s[nt]);
            s[nt] = MFMA_BF(Qh1, Kh[nt * 2 + 1], s[nt]);
            s[nt] = MFMA_BF(Qh0, Kl[nt * 2],     s[nt]);
            s[nt] = MFMA_BF(Qh1, Kl[nt * 2 + 1], s[nt]);
            s[nt] = MFMA_BF(Ql0, Kh[nt * 2],     s[nt]);
            s[nt] = MFMA_BF(Ql1, Kh[nt * 2 + 1], s[nt]);
        }

        // causal mask + per-row max (rows live on 16-lane groups)
        float mx[4] = {-3e38f, -3e38f, -3e38f, -3e38f};
        #pragma unroll
        for (int nt = 0; nt < 4; ++nt)
            #pragma unroll
            for (int reg = 0; reg < 4; ++reg) {
                if (j0 + nt * 16 + l16 > irow + reg) s[nt][reg] = -3e38f;
                mx[reg] = fmaxf(mx[reg], s[nt][reg]);
            }
        #pragma unroll
        for (int off = 8; off; off >>= 1)
            #pragma unroll
            for (int reg = 0; reg < 4; ++reg)
                mx[reg] = fmaxf(mx[reg], __shfl_xor(mx[reg], off));

        float al[4];
        #pragma unroll
        for (int reg = 0; reg < 4; ++reg) {
            const float mn = fmaxf(mrow[reg], mx[reg]);
            al[reg] = exp2f(mrow[reg] - mn);
            mrow[reg] = mn;
        }
        #pragma unroll
        for (int nt = 0; nt < 4; ++nt)
            #pragma unroll
            for (int reg = 0; reg < 4; ++reg) {
                const float p = (j0 + nt * 16 + l16 > irow + reg)
                                    ? 0.f : exp2f(s[nt][reg] - mrow[reg]);
                pw[(quad * 4 + reg) * 72 + nt * 16 + l16] = (_Float16)p;
            }
        #pragma unroll
        for (int nt = 0; nt < 4; ++nt)
            #pragma unroll
            for (int reg = 0; reg < 4; ++reg)
                o[nt][reg] *= al[reg];
        #pragma unroll
        for (int reg = 0; reg < 4; ++reg)
            o4[reg] *= al[reg];

        // PV: A = P (wave-private LDS, in-order per wave), B = V (prefetched)
        v8h Pa0 = *(const v8h*)(pw + l16 * 72 + quad * 8);
        v8h Pa1 = *(const v8h*)(pw + l16 * 72 + 32 + quad * 8);
        #pragma unroll
        for (int nt = 0; nt < 4; ++nt) {
            o[nt] = MFMA_F16(Pa0, Vf[nt * 2],     o[nt]);
            o[nt] = MFMA_F16(Pa1, Vf[nt * 2 + 1], o[nt]);
        }
        o4 = MFMA_F16(Pa0, vones, o4);      // row-sums of P (all cols equal)
        o4 = MFMA_F16(Pa1, vones, o4);
    }

    // merge the 4 key-split waves
    if (l16 == 0) {
        #pragma unroll
        for (int reg = 0; reg < 4; ++reg) {
            sm[w][quad * 4 + reg] = mrow[reg];
            sl[w][quad * 4 + reg] = o4[reg];
        }
    }
    __syncthreads();   // also fences last ps reads before os overwrite
    float sc[4];
    #pragma unroll
    for (int reg = 0; reg < 4; ++reg) {
        const int r = quad * 4 + reg;
        float M = sm[0][r];
        #pragma unroll
        for (int i = 1; i < 4; ++i) M = fmaxf(M, sm[i][r]);
        sc[reg] = exp2f(mrow[reg] - M);
    }
    float* ow = os + w * (16 * 68);
    #pragma unroll
    for (int nt = 0; nt < 4; ++nt)
        #pragma unroll
        for (int reg = 0; reg < 4; ++reg)
            ow[(quad * 4 + reg) * 68 + nt * 16 + l16] = o[nt][reg] * sc[reg];
    __syncthreads();

    #pragma unroll
    for (int kk = 0; kk < 4; ++kk) {
        const int m = w * 4 + kk;
        float M = sm[0][m];
        #pragma unroll
        for (int i = 1; i < 4; ++i) M = fmaxf(M, sm[i][m]);
        float L = 0.f, val = 0.f;
        #pragma unroll
        for (int i = 0; i < 4; ++i) {
            L   += sl[i][m] * exp2f(sm[i][m] - M);
            val += os[i * (16 * 68) + m * 68 + lane];
        }
        out[((size_t)b * TT + q0 + m) * HS + lane] = val / L;
    }
}

// ---------------------------------------------------------------------------
extern "C" void kernel_launch(void* const* d_in, const int* in_sizes, int n_in,
                              void* d_out, int out_size, void* d_ws, size_t ws_size,
                              hipStream_t stream)
{
    const float* x  = (const float*)d_in[0];
    const float* Wq = (const float*)d_in[1];
    const float* bq = (const float*)d_in[2];
    const float* Wk = (const float*)d_in[3];
    const float* bk = (const float*)d_in[4];
    const float* Wv = (const float*)d_in[5];
    const float* bv = (const float*)d_in[6];
    float* out = (float*)d_out;

    const int rows = in_sizes[0] / NE;   // 8192
    char* p = (char*)d_ws;
    __bf16* wth = (__bf16*)p;                 p += (size_t)192 * NE * 2;
    __bf16* wtl = (__bf16*)p;                 p += (size_t)192 * NE * 2;
    __bf16* qhb = (__bf16*)p;                 p += (size_t)rows * HS * 2;
    __bf16* qlb = (__bf16*)p;                 p += (size_t)rows * HS * 2;
    __bf16* khb = (__bf16*)p;                 p += (size_t)rows * HS * 2;
    __bf16* klb = (__bf16*)p;                 p += (size_t)rows * HS * 2;
    _Float16* vtb = (_Float16*)p;             p += (size_t)rows * HS * 2;

    prep_w<<<dim3(16, 3), 256, 0, stream>>>(Wq, Wk, Wv, wth, wtl);
    proj<<<dim3(rows / 64, 4), 512, 0, stream>>>(x, wth, wtl, bq, bk, bv,
                                                 qhb, qlb, khb, klb, vtb);
    attn<<<rows / 16, 256, 0, stream>>>(qhb, qlb, khb, klb, vtb, out);
}

// Round 6
// 147.787 us; speedup vs baseline: 1.1987x; 1.1987x over previous
//
#include <hip/hip_runtime.h>
#include <math.h>

// B=4, T=2048, N_EMBD=1024, HEAD=64.
// Reference multiplies scores by sqrt(64)=8; we fold 8*log2(e) into q and use exp2.
#define NE 1024
#define HS 64
#define TT 2048
#define QSC 11.541560327111707f   // 8 * log2(e)

typedef __bf16    v8bf __attribute__((ext_vector_type(8)));
typedef _Float16  v8h  __attribute__((ext_vector_type(8)));
typedef float     v4f  __attribute__((ext_vector_type(4)));

#define MFMA_BF(a, b, c)  __builtin_amdgcn_mfma_f32_16x16x32_bf16((a), (b), (c), 0, 0, 0)
#define MFMA_F16(a, b, c) __builtin_amdgcn_mfma_f32_16x16x32_f16((a), (b), (c), 0, 0, 0)

// async global->LDS DMA, 16 B per lane (lands at wave-uniform base + lane*16)
__device__ __forceinline__ void gl_lds16(const void* g, void* l) {
    __builtin_amdgcn_global_load_lds(
        (const __attribute__((address_space(1))) unsigned int*)g,
        (__attribute__((address_space(3))) unsigned int*)l, 16, 0, 0);
}

// ---------------------------------------------------------------------------
// prep_w: build the W "image" — hi/lo bf16, pre-arranged so that a linear
// global_load_lds stream lands B-fragments in LDS with an XOR-16B swizzle.
// Image layout (bytes): [step 0..31][ct 0..11][plane hi/lo][c 0..15][p16 0..3][16B]
//   content of (step,ct,pl,c,p16) = W[k = step*32 + (p16^(c&3))*8 + j][n = ct*16+c]
// Grid: (16 k-patches of 64, 3 matrices), 256 threads.
// ---------------------------------------------------------------------------
__global__ __launch_bounds__(256) void prep_w(
    const float* __restrict__ Wq, const float* __restrict__ Wk,
    const float* __restrict__ Wv, char* __restrict__ imgW)
{
    __shared__ float t[64][65];
    const int bx = blockIdx.x, by = blockIdx.y;
    const float* W = (by == 0) ? Wq : ((by == 1) ? Wk : Wv);
    const int tid = threadIdx.x;
    const int cc = tid & 63, r4 = tid >> 6;
    #pragma unroll
    for (int p = 0; p < 16; ++p) {
        const int k = p * 4 + r4;
        t[k][cc] = W[(size_t)(bx * 64 + k) * HS + cc];   // coalesced
    }
    __syncthreads();
    #pragma unroll
    for (int e = 0; e < 4; ++e) {
        const int chunk = tid + e * 256;           // 1024 chunks per block
        const int s2   = chunk >> 9;               // local step (0..1)
        const int rem  = chunk & 511;
        const int ctl  = rem >> 7;                 // local col-tile (0..3)
        const int rem2 = rem & 127;
        const int pl   = rem2 >> 6;                // plane 0=hi 1=lo
        const int rem3 = rem2 & 63;
        const int c    = rem3 >> 2;                // col in tile (0..15)
        const int p16  = rem3 & 3;                 // physical 16B slot
        const int kb   = s2 * 32 + ((p16 ^ (c & 3)) << 3);
        const int ncol = ctl * 16 + c;
        v8bf o;
        #pragma unroll
        for (int j = 0; j < 8; ++j) {
            const float v = t[kb + j][ncol];
            const __bf16 h = (__bf16)v;
            o[j] = pl ? (__bf16)(v - (float)h) : h;
        }
        *(v8bf*)(imgW + (size_t)(bx * 2 + s2) * 24576
                 + (by * 4 + ctl) * 2048 + pl * 1024 + c * 64 + p16 * 16) = o;
    }
}

// ---------------------------------------------------------------------------
// Projection GEMM: 256 blocks x 512 threads, block = 32 rows x all 192 cols,
// full K. x read ONCE from HBM; W slice (768 KB) from L2. Per BK=32 step,
// 28 KB staged async via global_load_lds (dbuf, m97 2-barrier K-loop):
//   xbuf: [row 0..31][p32 0..3][32B], content chunk c32 = p32 ^ (row&3)
//   wbuf: W image (above). XOR swizzles keep b128 reads <=4-way aliased.
// Waves: (rg 0..1: 16 rows) x (cg 0..3: 48 cols = 3 n-tiles), 9 MFMA/step.
// ---------------------------------------------------------------------------
__global__ __launch_bounds__(512, 2) void proj(
    const float* __restrict__ x, const char* __restrict__ imgW,
    const float* __restrict__ bq, const float* __restrict__ bk,
    const float* __restrict__ bv,
    __bf16* __restrict__ qh, __bf16* __restrict__ ql,
    __bf16* __restrict__ kh, __bf16* __restrict__ kl,
    _Float16* __restrict__ vt)
{
    __shared__ __align__(16) char sbuf[2][28672];   // [buf][x 4KB | W 24KB]

    const int tid = threadIdx.x, lane = tid & 63, w = tid >> 6;
    const int rg = w & 1, cg = w >> 1;
    const int quad = lane >> 4, l16 = lane & 15;
    const int m0 = blockIdx.x * 32;

    // staging sources: x chunk = tid (row=tid>>3, swizzled 32B slot), W linear
    const int xrow = tid >> 3;
    const int xc32 = ((tid & 7) >> 1) ^ (xrow & 3);
    const float* gx = x + (size_t)(m0 + xrow) * NE + xc32 * 8 + (tid & 1) * 4;
    const char*  gw = imgW + (size_t)tid * 16;

    v4f acc[3];
    #pragma unroll
    for (int i = 0; i < 3; ++i) acc[i] = (v4f){0.f, 0.f, 0.f, 0.f};

    #define STAGE(ks, b)  do {                                        \
        char* xb_ = sbuf[(b)];                                        \
        if (tid < 256) gl_lds16(gx + (ks) * 32, xb_ + tid * 16);      \
        const char* gws_ = gw + (size_t)(ks) * 24576;                 \
        gl_lds16(gws_,         xb_ + 4096  + tid * 16);               \
        gl_lds16(gws_ + 8192,  xb_ + 12288 + tid * 16);               \
        gl_lds16(gws_ + 16384, xb_ + 20480 + tid * 16);               \
    } while (0)

    STAGE(0, 0);
    __syncthreads();

    for (int ks = 0; ks < 32; ++ks) {
        const int b = ks & 1;
        if (ks < 31) STAGE(ks + 1, b ^ 1);

        const char* xb = sbuf[b];
        const char* wb = xb + 4096;
        // A fragment: row rl, swizzled 32B slot, convert fp32 -> hi/lo bf16
        const int rl = rg * 16 + l16;
        const int pA = quad ^ (rl & 3);
        const float4 a0 = *(const float4*)(xb + rl * 128 + pA * 32);
        const float4 a1 = *(const float4*)(xb + rl * 128 + pA * 32 + 16);
        const float av[8] = {a0.x, a0.y, a0.z, a0.w, a1.x, a1.y, a1.z, a1.w};
        v8bf ah, al;
        #pragma unroll
        for (int i = 0; i < 8; ++i) {
            const __bf16 h = (__bf16)av[i];
            ah[i] = h;
            al[i] = (__bf16)(av[i] - (float)h);
        }
        const int wo = l16 * 64 + ((quad ^ (l16 & 3)) << 4);
        #pragma unroll
        for (int j = 0; j < 3; ++j) {
            const char* base = wb + (cg * 3 + j) * 2048 + wo;
            const v8bf bh = *(const v8bf*)(base);
            const v8bf bl = *(const v8bf*)(base + 1024);
            acc[j] = MFMA_BF(ah, bh, acc[j]);
            acc[j] = MFMA_BF(ah, bl, acc[j]);
            acc[j] = MFMA_BF(al, bh, acc[j]);
        }
        __syncthreads();
    }
    #undef STAGE

    // epilogue: C layout col=l16 (within n-tile), row=quad*4+reg
    #pragma unroll
    for (int j = 0; j < 3; ++j) {
        const int n = cg * 48 + j * 16 + l16;
        const float bias = (n < 64) ? bq[n] : ((n < 128) ? bk[n - 64] : bv[n - 128]);
        #pragma unroll
        for (int reg = 0; reg < 4; ++reg) {
            const int row = m0 + rg * 16 + quad * 4 + reg;
            const float v = acc[j][reg] + bias;
            if (n < 64) {
                const float s = v * QSC;             // fold 8*log2e into q
                const __bf16 hh = (__bf16)s;
                qh[(size_t)row * HS + n] = hh;
                ql[(size_t)row * HS + n] = (__bf16)(s - (float)hh);
            } else if (n < 128) {
                const __bf16 hh = (__bf16)v;
                kh[(size_t)row * HS + n - 64] = hh;
                kl[(size_t)row * HS + n - 64] = (__bf16)(v - (float)hh);
            } else {
                const int b = row >> 11, tt = row & 2047, hc = n - 128;
                vt[((size_t)(b * HS + hc)) * TT + tt] = (_Float16)v;
            }
        }
    }
}

// ---------------------------------------------------------------------------
// Flash attention (unchanged from round 5 — verified). Block = 16 q-rows,
// 4 waves key-split, online softmax via exp2, ones-column row sums.
// ---------------------------------------------------------------------------
__global__ __launch_bounds__(256) void attn(
    const __bf16* __restrict__ qh, const __bf16* __restrict__ ql,
    const __bf16* __restrict__ kh, const __bf16* __restrict__ kl,
    const _Float16* __restrict__ vt, float* __restrict__ out)
{
    __shared__ __align__(16) char smem_raw[4 * 16 * 68 * 4];  // 17408 B
    _Float16* ps = (_Float16*)smem_raw;   // [w][16*72] fp16 (k-loop only)
    float*    os = (float*)smem_raw;      // [w][16*68] fp32 (merge only)
    __shared__ float sm[4][16], sl[4][16];

    const int tid = threadIdx.x, lane = tid & 63, w = tid >> 6;
    const int quad = lane >> 4, l16 = lane & 15;
    const int b = blockIdx.x & 3, qi = blockIdx.x >> 2;
    const int q0 = (127 - qi) * 16;                 // heavy tiles first

    const size_t qrow = ((size_t)b * TT + q0 + l16) * HS;
    const v8bf Qh0 = *(const v8bf*)(qh + qrow + quad * 8);
    const v8bf Qh1 = *(const v8bf*)(qh + qrow + 32 + quad * 8);
    const v8bf Ql0 = *(const v8bf*)(ql + qrow + quad * 8);
    const v8bf Ql1 = *(const v8bf*)(ql + qrow + 32 + quad * 8);

    const v8h vones = {(_Float16)1.f, (_Float16)1.f, (_Float16)1.f, (_Float16)1.f,
                       (_Float16)1.f, (_Float16)1.f, (_Float16)1.f, (_Float16)1.f};

    float mrow[4] = {-3e38f, -3e38f, -3e38f, -3e38f};
    v4f o[4], o4;
    #pragma unroll
    for (int i = 0; i < 4; ++i) o[i] = (v4f){0.f, 0.f, 0.f, 0.f};
    o4 = (v4f){0.f, 0.f, 0.f, 0.f};

    const int irow = q0 + quad * 4;                 // + reg
    const int ntk = (q0 + 16 + 63) >> 6;
    _Float16* pw = ps + w * (16 * 72);

    for (int t = w; t < ntk; t += 4) {
        const int j0 = t * 64;
        v8bf Kh[8], Kl[8];
        v8h  Vf[8];
        #pragma unroll
        for (int nt = 0; nt < 4; ++nt) {
            const size_t krow = ((size_t)b * TT + j0 + nt * 16 + l16) * HS;
            Kh[nt * 2]     = *(const v8bf*)(kh + krow + quad * 8);
            Kh[nt * 2 + 1] = *(const v8bf*)(kh + krow + 32 + quad * 8);
            Kl[nt * 2]     = *(const v8bf*)(kl + krow + quad * 8);
            Kl[nt * 2 + 1] = *(const v8bf*)(kl + krow + 32 + quad * 8);
        }
        #pragma unroll
        for (int nt = 0; nt < 4; ++nt) {
            const size_t vrow = ((size_t)(b * HS + nt * 16 + l16)) * TT + j0;
            Vf[nt * 2]     = *(const v8h*)(vt + vrow + quad * 8);
            Vf[nt * 2 + 1] = *(const v8h*)(vt + vrow + 32 + quad * 8);
        }

        v4f s[4];
        #pragma unroll
        for (int i = 0; i < 4; ++i) s[i] = (v4f){0.f, 0.f, 0.f, 0.f};
        #pragma unroll
        for (int nt = 0; nt < 4; ++nt) {
            s[nt] = MFMA_BF(Qh0, Kh[nt * 2],     s[nt]);
            s[nt] = MFMA_BF(Qh1, Kh[nt * 2 + 1], s[nt]);
            s[nt] = MFMA_BF(Qh0, Kl[nt * 2],     s[nt]);
            s[nt] = MFMA_BF(Qh1, Kl[nt * 2 + 1], s[nt]);
            s[nt] = MFMA_BF(Ql0, Kh[nt * 2],     s[nt]);
            s[nt] = MFMA_BF(Ql1, Kh[nt * 2 + 1], s[nt]);
        }

        float mx[4] = {-3e38f, -3e38f, -3e38f, -3e38f};
        #pragma unroll
        for (int nt = 0; nt < 4; ++nt)
            #pragma unroll
            for (int reg = 0; reg < 4; ++reg) {
                if (j0 + nt * 16 + l16 > irow + reg) s[nt][reg] = -3e38f;
                mx[reg] = fmaxf(mx[reg], s[nt][reg]);
            }
        #pragma unroll
        for (int off = 8; off; off >>= 1)
            #pragma unroll
            for (int reg = 0; reg < 4; ++reg)
                mx[reg] = fmaxf(mx[reg], __shfl_xor(mx[reg], off));

        float al[4];
        #pragma unroll
        for (int reg = 0; reg < 4; ++reg) {
            const float mn = fmaxf(mrow[reg], mx[reg]);
            al[reg] = exp2f(mrow[reg] - mn);
            mrow[reg] = mn;
        }
        #pragma unroll
        for (int nt = 0; nt < 4; ++nt)
            #pragma unroll
            for (int reg = 0; reg < 4; ++reg) {
                const float p = (j0 + nt * 16 + l16 > irow + reg)
                                    ? 0.f : exp2f(s[nt][reg] - mrow[reg]);
                pw[(quad * 4 + reg) * 72 + nt * 16 + l16] = (_Float16)p;
            }
        #pragma unroll
        for (int nt = 0; nt < 4; ++nt)
            #pragma unroll
            for (int reg = 0; reg < 4; ++reg)
                o[nt][reg] *= al[reg];
        #pragma unroll
        for (int reg = 0; reg < 4; ++reg)
            o4[reg] *= al[reg];

        v8h Pa0 = *(const v8h*)(pw + l16 * 72 + quad * 8);
        v8h Pa1 = *(const v8h*)(pw + l16 * 72 + 32 + quad * 8);
        #pragma unroll
        for (int nt = 0; nt < 4; ++nt) {
            o[nt] = MFMA_F16(Pa0, Vf[nt * 2],     o[nt]);
            o[nt] = MFMA_F16(Pa1, Vf[nt * 2 + 1], o[nt]);
        }
        o4 = MFMA_F16(Pa0, vones, o4);
        o4 = MFMA_F16(Pa1, vones, o4);
    }

    if (l16 == 0) {
        #pragma unroll
        for (int reg = 0; reg < 4; ++reg) {
            sm[w][quad * 4 + reg] = mrow[reg];
            sl[w][quad * 4 + reg] = o4[reg];
        }
    }
    __syncthreads();
    float sc[4];
    #pragma unroll
    for (int reg = 0; reg < 4; ++reg) {
        const int r = quad * 4 + reg;
        float M = sm[0][r];
        #pragma unroll
        for (int i = 1; i < 4; ++i) M = fmaxf(M, sm[i][r]);
        sc[reg] = exp2f(mrow[reg] - M);
    }
    float* ow = os + w * (16 * 68);
    #pragma unroll
    for (int nt = 0; nt < 4; ++nt)
        #pragma unroll
        for (int reg = 0; reg < 4; ++reg)
            ow[(quad * 4 + reg) * 68 + nt * 16 + l16] = o[nt][reg] * sc[reg];
    __syncthreads();

    #pragma unroll
    for (int kk = 0; kk < 4; ++kk) {
        const int m = w * 4 + kk;
        float M = sm[0][m];
        #pragma unroll
        for (int i = 1; i < 4; ++i) M = fmaxf(M, sm[i][m]);
        float L = 0.f, val = 0.f;
        #pragma unroll
        for (int i = 0; i < 4; ++i) {
            L   += sl[i][m] * exp2f(sm[i][m] - M);
            val += os[i * (16 * 68) + m * 68 + lane];
        }
        out[((size_t)b * TT + q0 + m) * HS + lane] = val / L;
    }
}

// ---------------------------------------------------------------------------
extern "C" void kernel_launch(void* const* d_in, const int* in_sizes, int n_in,
                              void* d_out, int out_size, void* d_ws, size_t ws_size,
                              hipStream_t stream)
{
    const float* x  = (const float*)d_in[0];
    const float* Wq = (const float*)d_in[1];
    const float* bq = (const float*)d_in[2];
    const float* Wk = (const float*)d_in[3];
    const float* bk = (const float*)d_in[4];
    const float* Wv = (const float*)d_in[5];
    const float* bv = (const float*)d_in[6];
    float* out = (float*)d_out;

    const int rows = in_sizes[0] / NE;   // 8192
    char* p = (char*)d_ws;
    char* imgW = p;                           p += (size_t)32 * 24576;      // 768 KB
    __bf16* qhb = (__bf16*)p;                 p += (size_t)rows * HS * 2;
    __bf16* qlb = (__bf16*)p;                 p += (size_t)rows * HS * 2;
    __bf16* khb = (__bf16*)p;                 p += (size_t)rows * HS * 2;
    __bf16* klb = (__bf16*)p;                 p += (size_t)rows * HS * 2;
    _Float16* vtb = (_Float16*)p;             p += (size_t)rows * HS * 2;

    prep_w<<<dim3(16, 3), 256, 0, stream>>>(Wq, Wk, Wv, imgW);
    proj<<<rows / 32, 512, 0, stream>>>(x, imgW, bq, bk, bv,
                                        qhb, qlb, khb, klb, vtb);
    attn<<<rows / 16, 256, 0, stream>>>(qhb, qlb, khb, klb, vtb, out);
}